// Round 4
// baseline (6019.840 us; speedup 1.0000x reference)
//
#include <hip/hip_runtime.h>
#include <hip/hip_bf16.h>

#define NBLK 512
#define NTHR 512
#define NWAVE (NBLK * (NTHR / 64))  // 4096 waves

__device__ __forceinline__ void grid_barrier(int* cnt, int* gen) {
  __syncthreads();
  if (threadIdx.x == 0) {
    __threadfence();  // agent-scope release: write back local L2
    int g = __hip_atomic_load(gen, __ATOMIC_RELAXED, __HIP_MEMORY_SCOPE_AGENT);
    int a = __hip_atomic_fetch_add(cnt, 1, __ATOMIC_ACQ_REL, __HIP_MEMORY_SCOPE_AGENT);
    if (a == NBLK - 1) {
      __hip_atomic_store(cnt, 0, __ATOMIC_RELAXED, __HIP_MEMORY_SCOPE_AGENT);
      __hip_atomic_store(gen, g + 1, __ATOMIC_RELEASE, __HIP_MEMORY_SCOPE_AGENT);
    } else {
      while (__hip_atomic_load(gen, __ATOMIC_RELAXED, __HIP_MEMORY_SCOPE_AGENT) == g)
        __builtin_amdgcn_s_sleep(8);
    }
    __threadfence();  // acquire: invalidate local caches
  }
  __syncthreads();
}

// One persistent kernel: all blocks resident (32KB LDS -> 5/CU by LDS; 128 VGPR cap
// -> 2/CU by regs; grid 512 = 2/CU on 256 CUs). Custom grid barrier between phases.
__global__ __launch_bounds__(NTHR, 4) void fused_gnn(
    const float* __restrict__ x, const int* __restrict__ srcp, const int* __restrict__ dstp,
    const float* __restrict__ edge_attr,
    const float* __restrict__ node_W, const float* __restrict__ node_b,
    const float* __restrict__ edge_W, const float* __restrict__ edge_b,
    const float* __restrict__ bn_g, const float* __restrict__ bn_b, const float* __restrict__ tv,
    const float* __restrict__ W1, const float* __restrict__ b1,
    const float* __restrict__ lng, const float* __restrict__ lnb,
    const float* __restrict__ W2, const float* __restrict__ b2,
    float* __restrict__ h, float* __restrict__ outv,
    int* deg, int* rowstart, int* fillptr, int* partials,
    int* bar_cnt, int* bar_gen, float* bnsums,
    int* csr_src, float* ea_csr,
    float* __restrict__ d_out, int N, int E) {
  __shared__ float shf[8192];  // 32 KB, reused per phase
  int* shi = (int*)shf;
  const int tid = threadIdx.x, lane = tid & 63, wid = tid >> 6;
  const int gtid = blockIdx.x * NTHR + tid;
  const int gwid = blockIdx.x * (NTHR / 64) + wid;

  // ---- P0: zero deg; h = x@node_W + node_b; layer-0 BN stats ----
  for (int i = gtid; i < N; i += NBLK * NTHR) deg[i] = 0;
  {
    float wc[8];
#pragma unroll
    for (int k = 0; k < 8; ++k) wc[k] = node_W[k * 64 + lane];
    float bc = node_b[lane];
    float s = 0.f, q = 0.f;
    int total = N * 64;
    for (int gid = gtid; gid < total; gid += NBLK * NTHR) {  // gid&63 == lane
      const float* xr = x + (size_t)(gid >> 6) * 8;
      float acc = bc;
#pragma unroll
      for (int k = 0; k < 8; ++k) acc = fmaf(xr[k], wc[k], acc);
      h[gid] = acc; s += acc; q = fmaf(acc, acc, q);
    }
    shf[wid * 64 + lane] = s; shf[512 + wid * 64 + lane] = q;
    __syncthreads();
    if (wid == 0) {
      float S = 0.f, Q = 0.f;
#pragma unroll
      for (int w = 0; w < 8; ++w) { S += shf[w * 64 + lane]; Q += shf[512 + w * 64 + lane]; }
      atomicAdd(&bnsums[lane], S);
      atomicAdd(&bnsums[64 + lane], Q);
    }
  }
  grid_barrier(bar_cnt, bar_gen);

  // ---- P1: degree histogram ----
  for (int e = gtid; e < E; e += NBLK * NTHR) atomicAdd(&deg[dstp[e]], 1);
  grid_barrier(bar_cnt, bar_gen);

  // ---- P2: per-block partial sums of deg ----
  const int CHUNK = (N + NBLK - 1) / NBLK;
  {
    int idx = blockIdx.x * CHUNK + tid;
    int v = (tid < CHUNK && idx < N) ? deg[idx] : 0;
    shi[tid] = v;
    __syncthreads();
    for (int o = 256; o > 0; o >>= 1) { if (tid < o) shi[tid] += shi[tid + o]; __syncthreads(); }
    if (tid == 0) partials[blockIdx.x] = shi[0];
  }
  grid_barrier(bar_cnt, bar_gen);

  // ---- P3: block 0 scans 512 partials -> exclusive prefix ----
  if (blockIdx.x == 0) {
    int v = partials[tid];
    shi[tid] = v;
    __syncthreads();
    for (int o = 1; o < NBLK; o <<= 1) {
      int add = (tid >= o) ? shi[tid - o] : 0;
      __syncthreads();
      shi[tid] += add;
      __syncthreads();
    }
    partials[tid] = shi[tid] - v;
  }
  grid_barrier(bar_cnt, bar_gen);

  // ---- P4: rowstart/fillptr = global exclusive prefix ----
  {
    int idx = blockIdx.x * CHUNK + tid;
    int v = (tid < CHUNK && idx < N) ? deg[idx] : 0;
    shi[tid] = (tid < CHUNK) ? v : 0;
    __syncthreads();
    for (int o = 1; o < NBLK; o <<= 1) {
      int add = (tid >= o) ? shi[tid - o] : 0;
      __syncthreads();
      shi[tid] += add;
      __syncthreads();
    }
    if (tid < CHUNK && idx < N) {
      int rs = partials[blockIdx.x] + shi[tid] - v;
      rowstart[idx] = rs; fillptr[idx] = rs;
    }
    if (gtid == 0) rowstart[N] = E;
  }
  grid_barrier(bar_cnt, bar_gen);

  // ---- P5: fill CSR (reorder edge_attr into CSR order) ----
  for (int e = gtid; e < E; e += NBLK * NTHR) {
    int d = dstp[e];
    int slot = atomicAdd(&fillptr[d], 1);
    csr_src[slot] = srcp[e];
    const float4* ap = (const float4*)(edge_attr + (size_t)e * 8);
    float4* op = (float4*)(ea_csr + (size_t)slot * 8);
    op[0] = ap[0]; op[1] = ap[1];
  }
  grid_barrier(bar_cnt, bar_gen);

  const float invN = 1.f / (float)N;
  for (int l = 0; l < 3; ++l) {
    // ---- P6: fused BN+ReLU + message + softmax aggregation (1 wave/node) ----
    {
      float mu = bnsums[l * 128 + lane] * invN;
      float var = bnsums[l * 128 + 64 + lane] * invN - mu * mu;
      float aa = rsqrtf(var + 1e-5f) * bn_g[l * 64 + lane];
      float cc = bn_b[l * 64 + lane] - mu * aa;
      float wcol[8];
#pragma unroll
      for (int k = 0; k < 8; ++k) wcol[k] = edge_W[k * 64 + lane];
      float eb = edge_b[lane];
      float tt = tv[l];
      for (int node = gwid; node < N; node += NWAVE) {
        int s0 = __builtin_amdgcn_readfirstlane(rowstart[node]);
        int s1 = __builtin_amdgcn_readfirstlane(rowstart[node + 1]);
        float hd = fmaxf(fmaf(h[(size_t)node * 64 + lane], aa, cc), 0.f);
        float den = 0.f, num = 0.f;
        for (int base = s0; base < s1; base += 64) {
          int myi = base + lane;
          int srcs = (myi < s1) ? csr_src[myi] : 0;
          int cnt = min(64, s1 - base);
          for (int jj = 0; jj < cnt; ++jj) {
            int sidx = __shfl(srcs, jj, 64);
            const float4* ea4 = (const float4*)(ea_csr + (size_t)(base + jj) * 8);
            float4 e0 = ea4[0], e1 = ea4[1];
            float hv = fmaxf(fmaf(h[(size_t)sidx * 64 + lane], aa, cc), 0.f);
            float ev = eb;
            ev = fmaf(e0.x, wcol[0], ev); ev = fmaf(e0.y, wcol[1], ev);
            ev = fmaf(e0.z, wcol[2], ev); ev = fmaf(e0.w, wcol[3], ev);
            ev = fmaf(e1.x, wcol[4], ev); ev = fmaf(e1.y, wcol[5], ev);
            ev = fmaf(e1.z, wcol[6], ev); ev = fmaf(e1.w, wcol[7], ev);
            float msg = fmaxf(hv + ev, 0.f) + 1e-7f;
            float p = __expf(msg * tt);
            den += p;
            num = fmaf(p, msg, num);
          }
        }
        outv[(size_t)node * 64 + lane] = num / fmaxf(den, 1e-16f) + hd;
      }
    }
    grid_barrier(bar_cnt, bar_gen);

    // ---- P7: MLP (64->128 LN ReLU ->64) + residual + next-layer BN stats ----
    {
      const float* W1g = W1 + (size_t)l * 8192;
      const float* W2g = W2 + (size_t)l * 8192;
      float b1a = b1[l * 128 + 2 * lane], b1b = b1[l * 128 + 2 * lane + 1];
      float ga = lng[l * 128 + 2 * lane], gb = lng[l * 128 + 2 * lane + 1];
      float la = lnb[l * 128 + 2 * lane], lb = lnb[l * 128 + 2 * lane + 1];
      float b2d = b2[l * 64 + lane];
      float* hout = (l == 2) ? d_out : h;
      float* zw = shf + wid * 1024;  // per-wave [8 nodes][128]
      float s = 0.f, q = 0.f;
      int ngroups = (N + 7) >> 3;
      for (int grp = gwid; grp < ngroups; grp += NWAVE) {
        int node0 = grp * 8;
#pragma unroll
        for (int j = 0; j < 8; ++j) {
          int nd = node0 + j;
          zw[j * 128 + lane] = (nd < N) ? outv[(size_t)nd * 64 + lane] : 0.f;
        }
        float2 acc[8];
#pragma unroll
        for (int j = 0; j < 8; ++j) acc[j] = make_float2(b1a, b1b);
#pragma unroll
        for (int c4 = 0; c4 < 16; ++c4) {
          float4 o[8];
#pragma unroll
          for (int j = 0; j < 8; ++j) o[j] = *(const float4*)&zw[j * 128 + c4 * 4];
#pragma unroll
          for (int kk = 0; kk < 4; ++kk) {
            float2 w = *(const float2*)&W1g[(c4 * 4 + kk) * 128 + 2 * lane];
#pragma unroll
            for (int j = 0; j < 8; ++j) {
              float oc = kk == 0 ? o[j].x : kk == 1 ? o[j].y : kk == 2 ? o[j].z : o[j].w;
              acc[j].x = fmaf(oc, w.x, acc[j].x);
              acc[j].y = fmaf(oc, w.y, acc[j].y);
            }
          }
        }
#pragma unroll
        for (int j = 0; j < 8; ++j) {
          float sx = acc[j].x + acc[j].y;
          float sq2 = fmaf(acc[j].x, acc[j].x, acc[j].y * acc[j].y);
#pragma unroll
          for (int o2 = 1; o2 < 64; o2 <<= 1) {
            sx += __shfl_xor(sx, o2, 64);
            sq2 += __shfl_xor(sq2, o2, 64);
          }
          float mu2 = sx * (1.f / 128.f);
          float var2 = sq2 * (1.f / 128.f) - mu2 * mu2;
          float rstd = rsqrtf(var2 + 1e-5f);
          float z0 = fmaxf((acc[j].x - mu2) * rstd * ga + la, 0.f);
          float z1 = fmaxf((acc[j].y - mu2) * rstd * gb + lb, 0.f);
          *(float2*)&zw[j * 128 + 2 * lane] = make_float2(z0, z1);
        }
        float accd[8];
#pragma unroll
        for (int j = 0; j < 8; ++j) accd[j] = b2d;
#pragma unroll
        for (int h4 = 0; h4 < 32; ++h4) {
          float4 z[8];
#pragma unroll
          for (int j = 0; j < 8; ++j) z[j] = *(const float4*)&zw[j * 128 + h4 * 4];
#pragma unroll
          for (int kk = 0; kk < 4; ++kk) {
            float w = W2g[(h4 * 4 + kk) * 64 + lane];
#pragma unroll
            for (int j = 0; j < 8; ++j) {
              float zc = kk == 0 ? z[j].x : kk == 1 ? z[j].y : kk == 2 ? z[j].z : z[j].w;
              accd[j] = fmaf(zc, w, accd[j]);
            }
          }
        }
#pragma unroll
        for (int j = 0; j < 8; ++j) {
          int nd = node0 + j;
          if (nd < N) {
            float v = h[(size_t)nd * 64 + lane] + accd[j];
            hout[(size_t)nd * 64 + lane] = v;
            if (l < 2) { s += v; q = fmaf(v, v, q); }
          }
        }
      }
      if (l < 2) {
        __syncthreads();
        shf[wid * 64 + lane] = s; shf[512 + wid * 64 + lane] = q;
        __syncthreads();
        if (wid == 0) {
          float S = 0.f, Q = 0.f;
#pragma unroll
          for (int w = 0; w < 8; ++w) { S += shf[w * 64 + lane]; Q += shf[512 + w * 64 + lane]; }
          atomicAdd(&bnsums[(l + 1) * 128 + lane], S);
          atomicAdd(&bnsums[(l + 1) * 128 + 64 + lane], Q);
        }
      }
    }
    grid_barrier(bar_cnt, bar_gen);
  }
}

extern "C" void kernel_launch(void* const* d_in, const int* in_sizes, int n_in,
                              void* d_out, int out_size, void* d_ws, size_t ws_size,
                              hipStream_t stream) {
  const float* x = (const float*)d_in[0];
  const int* edge_index = (const int*)d_in[1];
  const float* edge_attr = (const float*)d_in[2];
  const float* node_W = (const float*)d_in[3];
  const float* node_b = (const float*)d_in[4];
  const float* edge_W = (const float*)d_in[5];
  const float* edge_b = (const float*)d_in[6];
  const float* bn_g = (const float*)d_in[7];
  const float* bn_b = (const float*)d_in[8];
  const float* t = (const float*)d_in[9];
  const float* W1 = (const float*)d_in[10];
  const float* b1 = (const float*)d_in[11];
  const float* ln_g = (const float*)d_in[12];
  const float* ln_b = (const float*)d_in[13];
  const float* W2 = (const float*)d_in[14];
  const float* b2 = (const float*)d_in[15];

  int N = in_sizes[0] / 8;
  int E = in_sizes[1] / 2;
  const int* srcp = edge_index;
  const int* dstp = edge_index + E;

  char* ws = (char*)d_ws;
  size_t off = 0;
  auto alloc = [&](size_t bytes) {
    char* p = ws + off;
    off = (off + bytes + 255) & ~(size_t)255;
    return p;
  };
  int* bar = (int*)alloc(8);                       // counter, gen
  float* bnsums = (float*)alloc(3 * 128 * 4);      // 3 layers x (sum,sumsq)x64
  int* deg = (int*)alloc((size_t)N * 4);
  int* rowstart = (int*)alloc(((size_t)N + 1) * 4);
  int* fillptr = (int*)alloc((size_t)N * 4);
  int* partials = (int*)alloc(NBLK * 4);
  int* csr_src = (int*)alloc((size_t)E * 4);
  float* ea_csr = (float*)alloc((size_t)E * 8 * 4);
  float* h = (float*)alloc((size_t)N * 64 * 4);
  float* outv = (float*)alloc((size_t)N * 64 * 4);
  (void)ws_size; (void)n_in; (void)out_size;

  hipMemsetAsync(bar, 0, 8, stream);
  hipMemsetAsync(bnsums, 0, 3 * 128 * 4, stream);
  fused_gnn<<<NBLK, NTHR, 0, stream>>>(
      x, srcp, dstp, edge_attr, node_W, node_b, edge_W, edge_b, bn_g, bn_b, t,
      W1, b1, ln_g, ln_b, W2, b2,
      h, outv, deg, rowstart, fillptr, partials, bar, bar + 1, bnsums,
      csr_src, ea_csr, (float*)d_out, N, E);
}

// Round 5
// 3042.585 us; speedup vs baseline: 1.9785x; 1.9785x over previous
//
#include <hip/hip_runtime.h>
#include <hip/hip_bf16.h>

constexpr int HDIM = 8;
constexpr int EDIM = 8;

// h = x @ node_W + node_b, fused with layer-0 BN stats and deg zeroing.
__global__ __launch_bounds__(256) void init_h_stats_kernel(
    const float* __restrict__ x, const float* __restrict__ W, const float* __restrict__ b,
    float* __restrict__ h, float* __restrict__ sums, int* __restrict__ deg, int n) {
  __shared__ float reds[256], redq[256];
  int tid = threadIdx.x, lane = tid & 63;
  int gtid = blockIdx.x * 256 + tid;
  for (int i = gtid; i < n; i += 512 * 256) deg[i] = 0;
  float wc[HDIM];
#pragma unroll
  for (int k = 0; k < HDIM; ++k) wc[k] = W[k * 64 + lane];
  float bc = b[lane];
  float s = 0.f, q = 0.f;
  int total = n * 64;
  for (int gid = gtid; gid < total; gid += 512 * 256) {
    int row = gid >> 6;
    const float* xr = x + (size_t)row * HDIM;
    float acc = bc;
#pragma unroll
    for (int k = 0; k < HDIM; ++k) acc = fmaf(xr[k], wc[k], acc);
    h[gid] = acc;
    s += acc;
    q = fmaf(acc, acc, q);
  }
  reds[tid] = s; redq[tid] = q;
  __syncthreads();
  if (tid < 64) {
    float S = reds[tid] + reds[64 + tid] + reds[128 + tid] + reds[192 + tid];
    float Q = redq[tid] + redq[64 + tid] + redq[128 + tid] + redq[192 + tid];
    atomicAdd(&sums[tid], S);
    atomicAdd(&sums[64 + tid], Q);
  }
}

__global__ void deg_kernel(const int* __restrict__ dst, int* __restrict__ deg, int E) {
  int e = blockIdx.x * 256 + threadIdx.x;
  if (e < E) atomicAdd(&deg[dst[e]], 1);
}

__global__ void scan_kernel(const int* __restrict__ deg, int* __restrict__ rowstart,
                            int* __restrict__ fillptr, int n, int total) {
  __shared__ int part[1024];
  int tid = threadIdx.x;
  int chunk = (n + 1023) >> 10;
  int lo = tid * chunk, hi = min(n, lo + chunk);
  int s = 0;
  for (int i = lo; i < hi; ++i) s += deg[i];
  part[tid] = s;
  __syncthreads();
  for (int offd = 1; offd < 1024; offd <<= 1) {
    int add = (tid >= offd) ? part[tid - offd] : 0;
    __syncthreads();
    part[tid] += add;
    __syncthreads();
  }
  int run = (tid == 0) ? 0 : part[tid - 1];
  for (int i = lo; i < hi; ++i) {
    rowstart[i] = run; fillptr[i] = run;
    run += deg[i];
  }
  if (tid == 1023) rowstart[n] = total;
}

__global__ void fill_kernel(const int* __restrict__ src, const int* __restrict__ dst,
                            const float* __restrict__ edge_attr, int* __restrict__ fillptr,
                            int* __restrict__ csr_src, float* __restrict__ ea_csr, int E) {
  int e = blockIdx.x * 256 + threadIdx.x;
  if (e >= E) return;
  int d = dst[e];
  int slot = atomicAdd(&fillptr[d], 1);
  csr_src[slot] = src[e];
  const float4* ap = (const float4*)(edge_attr + (size_t)e * EDIM);
  float4* op = (float4*)(ea_csr + (size_t)slot * EDIM);
  op[0] = ap[0];
  op[1] = ap[1];
}

// Fused BN+ReLU + message + softmax-agg. 1 wave/node, lane=channel.
// Edge loop unrolled x4: all 4 h-gathers + ea loads in flight before consumption.
__global__ __launch_bounds__(256) void aggregate_kernel(
    const float* __restrict__ h, const float* __restrict__ sums,
    const float* __restrict__ bn_g, const float* __restrict__ bn_b,
    const int* __restrict__ rowstart, const int* __restrict__ csr_src,
    const float* __restrict__ ea_csr, const float* __restrict__ edge_W,
    const float* __restrict__ edge_b, const float* __restrict__ t,
    float* __restrict__ out, int n, float invN) {
  int lane = threadIdx.x & 63;
  int node = blockIdx.x * 4 + (threadIdx.x >> 6);
  if (node >= n) return;
  float mu = sums[lane] * invN;
  float var = sums[64 + lane] * invN - mu * mu;
  float aa = rsqrtf(var + 1e-5f) * bn_g[lane];
  float cc = bn_b[lane] - mu * aa;
  float wcol[EDIM];
#pragma unroll
  for (int k = 0; k < EDIM; ++k) wcol[k] = edge_W[k * 64 + lane];
  float eb = edge_b[lane];
  float tt = t[0];
  int s0 = __builtin_amdgcn_readfirstlane(rowstart[node]);
  int s1 = __builtin_amdgcn_readfirstlane(rowstart[node + 1]);
  float hd = fmaxf(fmaf(h[(size_t)node * 64 + lane], aa, cc), 0.f);
  float den = 0.f, num = 0.f;
  for (int base = s0; base < s1; base += 64) {
    int myi = base + lane;
    int srcs = (myi < s1) ? csr_src[myi] : 0;
    int cnt = min(64, s1 - base);
    int jj = 0;
    for (; jj + 4 <= cnt; jj += 4) {
      int i0 = __shfl(srcs, jj, 64);
      int i1 = __shfl(srcs, jj + 1, 64);
      int i2 = __shfl(srcs, jj + 2, 64);
      int i3 = __shfl(srcs, jj + 3, 64);
      float hv0 = h[(size_t)i0 * 64 + lane];
      float hv1 = h[(size_t)i1 * 64 + lane];
      float hv2 = h[(size_t)i2 * 64 + lane];
      float hv3 = h[(size_t)i3 * 64 + lane];
      const float4* ep = (const float4*)(ea_csr + (size_t)(base + jj) * EDIM);
      float4 a0 = ep[0], c0 = ep[1], a1 = ep[2], c1 = ep[3];
      float4 a2 = ep[4], c2 = ep[5], a3 = ep[6], c3 = ep[7];
#define EDGE_STEP(HV, A, C)                                                   \
      {                                                                        \
        float ev = eb;                                                         \
        ev = fmaf(A.x, wcol[0], ev); ev = fmaf(A.y, wcol[1], ev);              \
        ev = fmaf(A.z, wcol[2], ev); ev = fmaf(A.w, wcol[3], ev);              \
        ev = fmaf(C.x, wcol[4], ev); ev = fmaf(C.y, wcol[5], ev);              \
        ev = fmaf(C.z, wcol[6], ev); ev = fmaf(C.w, wcol[7], ev);              \
        float hn = fmaxf(fmaf(HV, aa, cc), 0.f);                               \
        float msg = fmaxf(hn + ev, 0.f) + 1e-7f;                               \
        float p = __expf(msg * tt);                                            \
        den += p;                                                              \
        num = fmaf(p, msg, num);                                               \
      }
      EDGE_STEP(hv0, a0, c0)
      EDGE_STEP(hv1, a1, c1)
      EDGE_STEP(hv2, a2, c2)
      EDGE_STEP(hv3, a3, c3)
    }
    for (; jj < cnt; ++jj) {
      int si = __shfl(srcs, jj, 64);
      float hv = h[(size_t)si * 64 + lane];
      const float4* ep = (const float4*)(ea_csr + (size_t)(base + jj) * EDIM);
      float4 a0 = ep[0], c0 = ep[1];
      EDGE_STEP(hv, a0, c0)
    }
#undef EDGE_STEP
  }
  out[(size_t)node * 64 + lane] = num / fmaxf(den, 1e-16f) + hd;
}

// MLP + residual + next-layer BN stats. 8 nodes/wave, weights straight from L2
// (same addr across waves -> broadcast). LDS only for activations (32 KB).
__global__ __launch_bounds__(512) void mlp_kernel(
    const float* __restrict__ outv, const float* __restrict__ h_in,
    const float* __restrict__ W1g, const float* __restrict__ b1,
    const float* __restrict__ lng, const float* __restrict__ lnb,
    const float* __restrict__ W2g, const float* __restrict__ b2,
    float* __restrict__ h_out, float* __restrict__ nextsums, int n) {
  __shared__ float zs[8][8][128];  // 32 KB
  int tid = threadIdx.x, lane = tid & 63, wid = tid >> 6;
  int ngroups = (n + 7) >> 3;
  int grp = blockIdx.x * 8 + wid;
  bool active = grp < ngroups;
  float s = 0.f, q = 0.f;
  if (active) {
    int node0 = grp * 8;
    float* zw = &zs[wid][0][0];
    float b1a = b1[2 * lane], b1b = b1[2 * lane + 1];
#pragma unroll
    for (int j = 0; j < 8; ++j) {
      int nd = node0 + j;
      zw[j * 128 + lane] = (nd < n) ? outv[(size_t)nd * 64 + lane] : 0.f;
    }
    float2 acc[8];
#pragma unroll
    for (int j = 0; j < 8; ++j) acc[j] = make_float2(b1a, b1b);
#pragma unroll
    for (int c4 = 0; c4 < 16; ++c4) {
      float4 o[8];
#pragma unroll
      for (int j = 0; j < 8; ++j) o[j] = *(const float4*)&zw[j * 128 + c4 * 4];
#pragma unroll
      for (int kk = 0; kk < 4; ++kk) {
        float2 w = *(const float2*)&W1g[(c4 * 4 + kk) * 128 + 2 * lane];
#pragma unroll
        for (int j = 0; j < 8; ++j) {
          float oc = kk == 0 ? o[j].x : kk == 1 ? o[j].y : kk == 2 ? o[j].z : o[j].w;
          acc[j].x = fmaf(oc, w.x, acc[j].x);
          acc[j].y = fmaf(oc, w.y, acc[j].y);
        }
      }
    }
    float ga = lng[2 * lane], gb = lng[2 * lane + 1];
    float la = lnb[2 * lane], lb = lnb[2 * lane + 1];
#pragma unroll
    for (int j = 0; j < 8; ++j) {
      float sx = acc[j].x + acc[j].y;
      float sq2 = fmaf(acc[j].x, acc[j].x, acc[j].y * acc[j].y);
#pragma unroll
      for (int o2 = 1; o2 < 64; o2 <<= 1) {
        sx += __shfl_xor(sx, o2, 64);
        sq2 += __shfl_xor(sq2, o2, 64);
      }
      float mu2 = sx * (1.f / 128.f);
      float var2 = sq2 * (1.f / 128.f) - mu2 * mu2;
      float rstd = rsqrtf(var2 + 1e-5f);
      float z0 = fmaxf((acc[j].x - mu2) * rstd * ga + la, 0.f);
      float z1 = fmaxf((acc[j].y - mu2) * rstd * gb + lb, 0.f);
      *(float2*)&zw[j * 128 + 2 * lane] = make_float2(z0, z1);
    }
    float b2d = b2[lane];
    float accd[8];
#pragma unroll
    for (int j = 0; j < 8; ++j) accd[j] = b2d;
#pragma unroll
    for (int h4 = 0; h4 < 32; ++h4) {
      float4 z[8];
#pragma unroll
      for (int j = 0; j < 8; ++j) z[j] = *(const float4*)&zw[j * 128 + h4 * 4];
#pragma unroll
      for (int kk = 0; kk < 4; ++kk) {
        float w = W2g[(h4 * 4 + kk) * 64 + lane];
#pragma unroll
        for (int j = 0; j < 8; ++j) {
          float zc = kk == 0 ? z[j].x : kk == 1 ? z[j].y : kk == 2 ? z[j].z : z[j].w;
          accd[j] = fmaf(zc, w, accd[j]);
        }
      }
    }
#pragma unroll
    for (int j = 0; j < 8; ++j) {
      int nd = node0 + j;
      if (nd < n) {
        float v = h_in[(size_t)nd * 64 + lane] + accd[j];
        h_out[(size_t)nd * 64 + lane] = v;
        s += v;
        q = fmaf(v, v, q);
      }
    }
  }
  if (nextsums != nullptr) {
    __syncthreads();
    float* red_s = &zs[0][0][0];
    float* red_q = &zs[0][0][0] + 1024;
    red_s[tid] = s;
    red_q[tid] = q;
    __syncthreads();
    if (tid < 64) {
      float S = 0.f, Q = 0.f;
#pragma unroll
      for (int w = 0; w < 8; ++w) { S += red_s[w * 64 + tid]; Q += red_q[w * 64 + tid]; }
      atomicAdd(&nextsums[tid], S);
      atomicAdd(&nextsums[64 + tid], Q);
    }
  }
}

extern "C" void kernel_launch(void* const* d_in, const int* in_sizes, int n_in,
                              void* d_out, int out_size, void* d_ws, size_t ws_size,
                              hipStream_t stream) {
  const float* x = (const float*)d_in[0];
  const int* edge_index = (const int*)d_in[1];
  const float* edge_attr = (const float*)d_in[2];
  const float* node_W = (const float*)d_in[3];
  const float* node_b = (const float*)d_in[4];
  const float* edge_W = (const float*)d_in[5];
  const float* edge_b = (const float*)d_in[6];
  const float* bn_g = (const float*)d_in[7];
  const float* bn_b = (const float*)d_in[8];
  const float* t = (const float*)d_in[9];
  const float* W1 = (const float*)d_in[10];
  const float* b1 = (const float*)d_in[11];
  const float* ln_g = (const float*)d_in[12];
  const float* ln_b = (const float*)d_in[13];
  const float* W2 = (const float*)d_in[14];
  const float* b2 = (const float*)d_in[15];

  int N = in_sizes[0] / HDIM;
  int E = in_sizes[1] / 2;
  const int* srcp = edge_index;
  const int* dstp = edge_index + E;

  char* ws = (char*)d_ws;
  size_t off = 0;
  auto alloc = [&](size_t bytes) {
    char* p = ws + off;
    off = (off + bytes + 255) & ~(size_t)255;
    return p;
  };
  int* deg = (int*)alloc((size_t)N * 4);
  int* rowstart = (int*)alloc(((size_t)N + 1) * 4);
  int* fillptr = (int*)alloc((size_t)N * 4);
  float* bnsums = (float*)alloc(3 * 128 * 4);
  int* csr_src = (int*)alloc((size_t)E * 4);
  float* ea_csr = (float*)alloc((size_t)E * EDIM * 4);
  float* h = (float*)alloc((size_t)N * 64 * 4);
  float* outv = (float*)alloc((size_t)N * 64 * 4);
  (void)ws_size; (void)n_in; (void)out_size;

  hipMemsetAsync(bnsums, 0, 3 * 128 * 4, stream);
  init_h_stats_kernel<<<512, 256, 0, stream>>>(x, node_W, node_b, h, bnsums, deg, N);
  deg_kernel<<<(E + 255) / 256, 256, 0, stream>>>(dstp, deg, E);
  scan_kernel<<<1, 1024, 0, stream>>>(deg, rowstart, fillptr, N, E);
  fill_kernel<<<(E + 255) / 256, 256, 0, stream>>>(srcp, dstp, edge_attr, fillptr, csr_src, ea_csr, E);

  float invN = 1.0f / (float)N;
  int ngroups = (N + 7) >> 3;
  int mlp_blocks = (ngroups + 7) / 8;
  for (int l = 0; l < 3; ++l) {
    aggregate_kernel<<<(N + 3) / 4, 256, 0, stream>>>(
        h, bnsums + l * 128, bn_g + l * 64, bn_b + l * 64, rowstart, csr_src, ea_csr,
        edge_W, edge_b, t + l, outv, N, invN);
    float* hout = (l == 2) ? (float*)d_out : h;
    float* nxt = (l == 2) ? nullptr : (bnsums + (l + 1) * 128);
    mlp_kernel<<<mlp_blocks, 512, 0, stream>>>(outv, h, W1 + (size_t)l * 8192, b1 + l * 128,
                                               ln_g + l * 128, ln_b + l * 128,
                                               W2 + (size_t)l * 8192, b2 + l * 64, hout, nxt, N);
  }
}

// Round 6
// 966.970 us; speedup vs baseline: 6.2255x; 3.1465x over previous
//
#include <hip/hip_runtime.h>
#include <hip/hip_bf16.h>

constexpr int HDIM = 8;
constexpr int EDIM = 8;

// h = x @ node_W + node_b, fused with layer-0 BN stats (8-slot) and deg zeroing.
__global__ __launch_bounds__(256) void init_h_stats_kernel(
    const float* __restrict__ x, const float* __restrict__ W, const float* __restrict__ b,
    float* __restrict__ h, float* __restrict__ sums, int* __restrict__ deg, int n) {
  __shared__ float reds[256], redq[256];
  int tid = threadIdx.x, lane = tid & 63;
  int gtid = blockIdx.x * 256 + tid;
  for (int i = gtid; i < n; i += 512 * 256) deg[i] = 0;
  float wc[HDIM];
#pragma unroll
  for (int k = 0; k < HDIM; ++k) wc[k] = W[k * 64 + lane];
  float bc = b[lane];
  float s = 0.f, q = 0.f;
  int total = n * 64;
  for (int gid = gtid; gid < total; gid += 512 * 256) {
    int row = gid >> 6;
    const float* xr = x + (size_t)row * HDIM;
    float acc = bc;
#pragma unroll
    for (int k = 0; k < HDIM; ++k) acc = fmaf(xr[k], wc[k], acc);
    h[gid] = acc;
    s += acc;
    q = fmaf(acc, acc, q);
  }
  reds[tid] = s; redq[tid] = q;
  __syncthreads();
  if (tid < 64) {
    float S = reds[tid] + reds[64 + tid] + reds[128 + tid] + reds[192 + tid];
    float Q = redq[tid] + redq[64 + tid] + redq[128 + tid] + redq[192 + tid];
    int slot = blockIdx.x & 7;
    atomicAdd(&sums[slot * 128 + tid], S);
    atomicAdd(&sums[slot * 128 + 64 + tid], Q);
  }
}

__global__ void deg_kernel(const int* __restrict__ dst, int* __restrict__ deg, int E) {
  int e = blockIdx.x * 256 + threadIdx.x;
  if (e < E) atomicAdd(&deg[dst[e]], 1);
}

__global__ void scan_kernel(const int* __restrict__ deg, int* __restrict__ rowstart,
                            int* __restrict__ fillptr, int n, int total) {
  __shared__ int part[1024];
  int tid = threadIdx.x;
  int chunk = (n + 1023) >> 10;
  int lo = tid * chunk, hi = min(n, lo + chunk);
  int s = 0;
  for (int i = lo; i < hi; ++i) s += deg[i];
  part[tid] = s;
  __syncthreads();
  for (int offd = 1; offd < 1024; offd <<= 1) {
    int add = (tid >= offd) ? part[tid - offd] : 0;
    __syncthreads();
    part[tid] += add;
    __syncthreads();
  }
  int run = (tid == 0) ? 0 : part[tid - 1];
  for (int i = lo; i < hi; ++i) {
    rowstart[i] = run; fillptr[i] = run;
    run += deg[i];
  }
  if (tid == 1023) rowstart[n] = total;
}

__global__ void fill_kernel(const int* __restrict__ src, const int* __restrict__ dst,
                            const float* __restrict__ edge_attr, int* __restrict__ fillptr,
                            int* __restrict__ csr_src, float* __restrict__ ea_csr, int E) {
  int e = blockIdx.x * 256 + threadIdx.x;
  if (e >= E) return;
  int d = dst[e];
  int slot = atomicAdd(&fillptr[d], 1);
  csr_src[slot] = src[e];
  const float4* ap = (const float4*)(edge_attr + (size_t)e * EDIM);
  float4* op = (float4*)(ea_csr + (size_t)slot * EDIM);
  op[0] = ap[0];
  op[1] = ap[1];
}

// Fused BN+ReLU + message + softmax-agg. 1 wave/node, lane=channel. Edge loop x4.
__global__ __launch_bounds__(256) void aggregate_kernel(
    const float* __restrict__ h, const float* __restrict__ sums,
    const float* __restrict__ bn_g, const float* __restrict__ bn_b,
    const int* __restrict__ rowstart, const int* __restrict__ csr_src,
    const float* __restrict__ ea_csr, const float* __restrict__ edge_W,
    const float* __restrict__ edge_b, const float* __restrict__ t,
    float* __restrict__ out, int n, float invN) {
  int lane = threadIdx.x & 63;
  int node = blockIdx.x * 4 + (threadIdx.x >> 6);
  if (node >= n) return;
  float ssum = 0.f, qsum = 0.f;
#pragma unroll
  for (int k = 0; k < 8; ++k) {
    ssum += sums[k * 128 + lane];
    qsum += sums[k * 128 + 64 + lane];
  }
  float mu = ssum * invN;
  float var = qsum * invN - mu * mu;
  float aa = rsqrtf(var + 1e-5f) * bn_g[lane];
  float cc = bn_b[lane] - mu * aa;
  float wcol[EDIM];
#pragma unroll
  for (int k = 0; k < EDIM; ++k) wcol[k] = edge_W[k * 64 + lane];
  float eb = edge_b[lane];
  float tt = t[0];
  int s0 = __builtin_amdgcn_readfirstlane(rowstart[node]);
  int s1 = __builtin_amdgcn_readfirstlane(rowstart[node + 1]);
  float hd = fmaxf(fmaf(h[(size_t)node * 64 + lane], aa, cc), 0.f);
  float den = 0.f, num = 0.f;
  for (int base = s0; base < s1; base += 64) {
    int myi = base + lane;
    int srcs = (myi < s1) ? csr_src[myi] : 0;
    int cnt = min(64, s1 - base);
    int jj = 0;
    for (; jj + 4 <= cnt; jj += 4) {
      int i0 = __shfl(srcs, jj, 64);
      int i1 = __shfl(srcs, jj + 1, 64);
      int i2 = __shfl(srcs, jj + 2, 64);
      int i3 = __shfl(srcs, jj + 3, 64);
      float hv0 = h[(size_t)i0 * 64 + lane];
      float hv1 = h[(size_t)i1 * 64 + lane];
      float hv2 = h[(size_t)i2 * 64 + lane];
      float hv3 = h[(size_t)i3 * 64 + lane];
      const float4* ep = (const float4*)(ea_csr + (size_t)(base + jj) * EDIM);
      float4 a0 = ep[0], c0 = ep[1], a1 = ep[2], c1 = ep[3];
      float4 a2 = ep[4], c2 = ep[5], a3 = ep[6], c3 = ep[7];
#define EDGE_STEP(HV, A, C)                                                   \
      {                                                                        \
        float ev = eb;                                                         \
        ev = fmaf(A.x, wcol[0], ev); ev = fmaf(A.y, wcol[1], ev);              \
        ev = fmaf(A.z, wcol[2], ev); ev = fmaf(A.w, wcol[3], ev);              \
        ev = fmaf(C.x, wcol[4], ev); ev = fmaf(C.y, wcol[5], ev);              \
        ev = fmaf(C.z, wcol[6], ev); ev = fmaf(C.w, wcol[7], ev);              \
        float hn = fmaxf(fmaf(HV, aa, cc), 0.f);                               \
        float msg = fmaxf(hn + ev, 0.f) + 1e-7f;                               \
        float p = __expf(msg * tt);                                            \
        den += p;                                                              \
        num = fmaf(p, msg, num);                                               \
      }
      EDGE_STEP(hv0, a0, c0)
      EDGE_STEP(hv1, a1, c1)
      EDGE_STEP(hv2, a2, c2)
      EDGE_STEP(hv3, a3, c3)
    }
    for (; jj < cnt; ++jj) {
      int si = __shfl(srcs, jj, 64);
      float hv = h[(size_t)si * 64 + lane];
      const float4* ep = (const float4*)(ea_csr + (size_t)(base + jj) * EDIM);
      float4 a0 = ep[0], c0 = ep[1];
      EDGE_STEP(hv, a0, c0)
    }
#undef EDGE_STEP
  }
  out[(size_t)node * 64 + lane] = num / fmaxf(den, 1e-16f) + hd;
}

// Node-per-lane MLP: 1 wave per 64-node tile. Lane owns a node; weights are
// wave-uniform LDS broadcasts; LN fully in-register; activations transposed
// through a pad-129 LDS buffer (conflict-free). No shfl, no per-node VMEM chains.
__global__ __launch_bounds__(64, 1) void mlp_lane_kernel(
    const float* __restrict__ outv, const float* __restrict__ h_in,
    const float* __restrict__ W1, const float* __restrict__ b1,
    const float* __restrict__ lng, const float* __restrict__ lnb,
    const float* __restrict__ W2, const float* __restrict__ b2,
    float* __restrict__ h_out, float* __restrict__ nextsums, int n) {
  __shared__ float wbuf[8192];        // 32 KB: W1, later W2 (union)
  __shared__ float sbuf[64 * 129];    // 33 KB: x -> z -> acc (union), pad 129
  __shared__ float4 b1v[32], lgv[32], lbv[32], b2v[16];
  const int l = threadIdx.x;
  const int n0 = blockIdx.x * 64;
  // stage W1 + biases + transpose-in
  {
    const float4* src = (const float4*)W1;
    float4* dst = (float4*)wbuf;
#pragma unroll
    for (int j = 0; j < 32; ++j) dst[j * 64 + l] = src[j * 64 + l];
    if (l < 32) {
      b1v[l] = ((const float4*)b1)[l];
      lgv[l] = ((const float4*)lng)[l];
      lbv[l] = ((const float4*)lnb)[l];
      if (l < 16) b2v[l] = ((const float4*)b2)[l];
    }
  }
#pragma unroll 8
  for (int r = 0; r < 64; ++r) {
    int nd = n0 + r;
    sbuf[r * 129 + l] = (nd < n) ? outv[(size_t)nd * 64 + l] : 0.f;
  }
  __syncthreads();
  // phase 1: y[128] = x @ W1 + b1 (per-lane node, y in VGPRs)
  float4 y[32];
#pragma unroll
  for (int j = 0; j < 32; ++j) y[j] = b1v[j];
  for (int c = 0; c < 64; ++c) {
    float xc = sbuf[l * 129 + c];
    const float4* wr = (const float4*)&wbuf[c * 128];
#pragma unroll
    for (int j = 0; j < 32; ++j) {
      float4 w = wr[j];
      y[j].x = fmaf(xc, w.x, y[j].x);
      y[j].y = fmaf(xc, w.y, y[j].y);
      y[j].z = fmaf(xc, w.z, y[j].z);
      y[j].w = fmaf(xc, w.w, y[j].w);
    }
  }
  // LayerNorm in-register (per-lane over 128)
  float s1 = 0.f, q1 = 0.f;
#pragma unroll
  for (int j = 0; j < 32; ++j) {
    s1 += y[j].x + y[j].y + y[j].z + y[j].w;
    q1 = fmaf(y[j].x, y[j].x, q1);
    q1 = fmaf(y[j].y, y[j].y, q1);
    q1 = fmaf(y[j].z, y[j].z, q1);
    q1 = fmaf(y[j].w, y[j].w, q1);
  }
  float mu = s1 * (1.f / 128.f);
  float var = q1 * (1.f / 128.f) - mu * mu;
  float rstd = rsqrtf(var + 1e-5f);
  __syncthreads();  // all x reads done; sbuf will hold z
#pragma unroll
  for (int j = 0; j < 32; ++j) {
    float4 g = lgv[j], bb = lbv[j];
    sbuf[l * 129 + 4 * j + 0] = fmaxf((y[j].x - mu) * rstd * g.x + bb.x, 0.f);
    sbuf[l * 129 + 4 * j + 1] = fmaxf((y[j].y - mu) * rstd * g.y + bb.y, 0.f);
    sbuf[l * 129 + 4 * j + 2] = fmaxf((y[j].z - mu) * rstd * g.z + bb.z, 0.f);
    sbuf[l * 129 + 4 * j + 3] = fmaxf((y[j].w - mu) * rstd * g.w + bb.w, 0.f);
  }
  __syncthreads();  // W1 reads done; wbuf will hold W2
  {
    const float4* src = (const float4*)W2;
    float4* dst = (float4*)wbuf;
#pragma unroll
    for (int j = 0; j < 32; ++j) dst[j * 64 + l] = src[j * 64 + l];
  }
  __syncthreads();
  // phase 2: acc[64] = z @ W2 + b2
  float4 acc[16];
#pragma unroll
  for (int j = 0; j < 16; ++j) acc[j] = b2v[j];
  for (int hh = 0; hh < 128; ++hh) {
    float zh = sbuf[l * 129 + hh];
    const float4* wr = (const float4*)&wbuf[hh * 64];
#pragma unroll
    for (int j = 0; j < 16; ++j) {
      float4 w = wr[j];
      acc[j].x = fmaf(zh, w.x, acc[j].x);
      acc[j].y = fmaf(zh, w.y, acc[j].y);
      acc[j].z = fmaf(zh, w.z, acc[j].z);
      acc[j].w = fmaf(zh, w.w, acc[j].w);
    }
  }
  __syncthreads();  // all z reads done; sbuf will hold acc (transpose-out)
#pragma unroll
  for (int j = 0; j < 16; ++j) {
    sbuf[l * 129 + 4 * j + 0] = acc[j].x;
    sbuf[l * 129 + 4 * j + 1] = acc[j].y;
    sbuf[l * 129 + 4 * j + 2] = acc[j].z;
    sbuf[l * 129 + 4 * j + 3] = acc[j].w;
  }
  __syncthreads();
  // residual + store (coalesced) + next-layer BN partial stats (channel = lane)
  float s = 0.f, q = 0.f;
#pragma unroll 8
  for (int r = 0; r < 64; ++r) {
    int nd = n0 + r;
    if (nd < n) {
      float v = h_in[(size_t)nd * 64 + l] + sbuf[r * 129 + l];
      h_out[(size_t)nd * 64 + l] = v;
      s += v;
      q = fmaf(v, v, q);
    }
  }
  if (nextsums != nullptr) {
    int slot = blockIdx.x & 7;
    atomicAdd(&nextsums[slot * 128 + l], s);
    atomicAdd(&nextsums[slot * 128 + 64 + l], q);
  }
}

extern "C" void kernel_launch(void* const* d_in, const int* in_sizes, int n_in,
                              void* d_out, int out_size, void* d_ws, size_t ws_size,
                              hipStream_t stream) {
  const float* x = (const float*)d_in[0];
  const int* edge_index = (const int*)d_in[1];
  const float* edge_attr = (const float*)d_in[2];
  const float* node_W = (const float*)d_in[3];
  const float* node_b = (const float*)d_in[4];
  const float* edge_W = (const float*)d_in[5];
  const float* edge_b = (const float*)d_in[6];
  const float* bn_g = (const float*)d_in[7];
  const float* bn_b = (const float*)d_in[8];
  const float* t = (const float*)d_in[9];
  const float* W1 = (const float*)d_in[10];
  const float* b1 = (const float*)d_in[11];
  const float* ln_g = (const float*)d_in[12];
  const float* ln_b = (const float*)d_in[13];
  const float* W2 = (const float*)d_in[14];
  const float* b2 = (const float*)d_in[15];

  int N = in_sizes[0] / HDIM;
  int E = in_sizes[1] / 2;
  const int* srcp = edge_index;
  const int* dstp = edge_index + E;

  char* ws = (char*)d_ws;
  size_t off = 0;
  auto alloc = [&](size_t bytes) {
    char* p = ws + off;
    off = (off + bytes + 255) & ~(size_t)255;
    return p;
  };
  int* deg = (int*)alloc((size_t)N * 4);
  int* rowstart = (int*)alloc(((size_t)N + 1) * 4);
  int* fillptr = (int*)alloc((size_t)N * 4);
  float* bnsums = (float*)alloc(3 * 1024 * 4);  // 3 layers x 8 slots x 128
  int* csr_src = (int*)alloc((size_t)E * 4);
  float* ea_csr = (float*)alloc((size_t)E * EDIM * 4);
  float* h = (float*)alloc((size_t)N * 64 * 4);
  float* outv = (float*)alloc((size_t)N * 64 * 4);
  (void)ws_size; (void)n_in; (void)out_size;

  hipMemsetAsync(bnsums, 0, 3 * 1024 * 4, stream);
  init_h_stats_kernel<<<512, 256, 0, stream>>>(x, node_W, node_b, h, bnsums, deg, N);
  deg_kernel<<<(E + 255) / 256, 256, 0, stream>>>(dstp, deg, E);
  scan_kernel<<<1, 1024, 0, stream>>>(deg, rowstart, fillptr, N, E);
  fill_kernel<<<(E + 255) / 256, 256, 0, stream>>>(srcp, dstp, edge_attr, fillptr, csr_src, ea_csr, E);

  float invN = 1.0f / (float)N;
  int mlp_blocks = (N + 63) / 64;
  for (int l = 0; l < 3; ++l) {
    aggregate_kernel<<<(N + 3) / 4, 256, 0, stream>>>(
        h, bnsums + l * 1024, bn_g + l * 64, bn_b + l * 64, rowstart, csr_src, ea_csr,
        edge_W, edge_b, t + l, outv, N, invN);
    float* hout = (l == 2) ? (float*)d_out : h;
    float* nxt = (l == 2) ? nullptr : (bnsums + (l + 1) * 1024);
    mlp_lane_kernel<<<mlp_blocks, 64, 0, stream>>>(outv, h, W1 + (size_t)l * 8192, b1 + l * 128,
                                                   ln_g + l * 128, ln_b + l * 128,
                                                   W2 + (size_t)l * 8192, b2 + l * 64, hout, nxt, N);
  }
}